// Round 1
// baseline (1449.448 us; speedup 1.0000x reference)
//
#include <hip/hip_runtime.h>
#include <hip/hip_fp16.h>
#include <hip/hip_bf16.h>
#include <cstdint>

#define TLEN  256
#define HD    128
#define BATCH 8
#define VOCAB 32000
#define EMBD  32

typedef __attribute__((ext_vector_type(8))) short short8v;
typedef __attribute__((ext_vector_type(4))) float f32x4;

__device__ __forceinline__ float tanhfast(float x){
  // tanh(x) = 1 - 2/(exp2(2x*log2e)+1); exp2 overflow/underflow saturate correctly.
  float e = __builtin_amdgcn_exp2f(x * 2.8853900817779268f);
  return 1.0f - 2.0f * __builtin_amdgcn_rcpf(e + 1.0f);
}
__device__ __forceinline__ unsigned short f2bf(float f){
  unsigned u = __float_as_uint(f);
  return (unsigned short)((u + 0x7fffu + ((u >> 16) & 1u)) >> 16);
}
__device__ __forceinline__ void gload_lds16(const void* g, void* l){
  __builtin_amdgcn_global_load_lds((const __attribute__((address_space(1))) void*)g,
                                   (__attribute__((address_space(3))) void*)l, 16, 0, 0);
}

// ---------------- prep 1: ex[b,t,c] = emb[x[b,t]] @ W_ih[0:32] + b_ih + b_hh ----------------
__global__ void prep_ex_kernel(const int* __restrict__ x, const float* __restrict__ emb,
                               const float* __restrict__ W_ih, const float* __restrict__ b_ih,
                               const float* __restrict__ b_hh, float* __restrict__ ex){
  int bt = blockIdx.x;
  int c  = threadIdx.x;
  int ix = x[bt];
  const float* er = emb + (long)ix * EMBD;
  float acc = b_ih[c] + b_hh[c];
  #pragma unroll
  for (int e = 0; e < EMBD; ++e) acc += er[e] * W_ih[e * HD + c];
  ex[bt * HD + c] = acc;
}

// ---------------- prep 2: Wbt[n][k] = bf16(W_out[k][n]) (transpose + convert) ----------------
__global__ void prep_wt_kernel(const float* __restrict__ W_out, unsigned short* __restrict__ Wbt){
  __shared__ float tile[32][33];
  int tx = threadIdx.x & 31, ty = threadIdx.x >> 5;
  int n0 = blockIdx.x * 32, k0 = blockIdx.y * 32;
  #pragma unroll
  for (int j = 0; j < 4; ++j){
    int k = ty + j * 8;
    tile[k][tx] = W_out[(long)(k0 + k) * VOCAB + n0 + tx];
  }
  __syncthreads();
  #pragma unroll
  for (int j = 0; j < 4; ++j){
    int n = ty + j * 8;
    Wbt[(long)(n0 + n) * HD + k0 + tx] = f2bf(tile[tx][n]);
  }
}

// ---------------- scan: one workgroup per batch element, persistent over t ----------------
// LDS: keys[256][128] fp16 | hid[256][128] fp16 | fp32 scratch
__launch_bounds__(1024)
__global__ void scan_kernel(const float* __restrict__ W_attn, const float* __restrict__ U_attn,
                            const float* __restrict__ v_attn, const float* __restrict__ W_ih,
                            const float* __restrict__ W_hh, const float* __restrict__ ex,
                            unsigned short* __restrict__ out_bf, float* __restrict__ h_final){
  extern __shared__ char lds[];
  unsigned short* keys = (unsigned short*)lds;                 // [TLEN][HD] fp16
  unsigned short* hid  = (unsigned short*)(lds + TLEN*HD*2);   // [TLEN][HD] fp16
  float* fbuf   = (float*)(lds + 2*TLEN*HD*2);
  float* h_lds  = fbuf;            // 128
  float* q_lds  = fbuf + HD;       // 128
  float* hh_lds = fbuf + 2*HD;     // 128
  float* ctx_lds= fbuf + 3*HD;     // 128
  float* ex_lds = fbuf + 4*HD;     // 128
  float* v_lds  = fbuf + 5*HD;     // 128
  float* scores = fbuf + 6*HD;     // 256
  float* pp     = fbuf + 6*HD + TLEN; // 16*128
  float* zr     = pp + 16*HD;      // 1

  const int b   = blockIdx.x;
  const int tid = threadIdx.x;
  const int lane = tid & 63, wv = tid >> 6;
  const int c_  = tid >> 3, rg = tid & 7;

  // ---- stage weights into VGPRs (coalesced global->LDS, then strided LDS->VGPR) ----
  float Wa[16], Ua[16], Wh[16], Wc[16];
  {
    float* stage = (float*)lds;  // reuse keys+hid area (64KB needed), rewritten later
    float4* d4 = (float4*)stage;
    {
      const float4* s4 = (const float4*)W_attn;
      for (int i = 0; i < 4; ++i) d4[tid + i*1024] = s4[tid + i*1024];
      __syncthreads();
      #pragma unroll
      for (int i = 0; i < 16; ++i) Wa[i] = stage[(rg*16 + i)*HD + c_];
      __syncthreads();
    }
    {
      const float4* s4 = (const float4*)U_attn;
      for (int i = 0; i < 4; ++i) d4[tid + i*1024] = s4[tid + i*1024];
      __syncthreads();
      #pragma unroll
      for (int i = 0; i < 16; ++i) Ua[i] = stage[(rg*16 + i)*HD + c_];
      __syncthreads();
    }
    {
      const float4* s4 = (const float4*)W_hh;
      for (int i = 0; i < 4; ++i) d4[tid + i*1024] = s4[tid + i*1024];
      __syncthreads();
      #pragma unroll
      for (int i = 0; i < 16; ++i) Wh[i] = stage[(rg*16 + i)*HD + c_];
      __syncthreads();
    }
    {
      const float4* s4 = (const float4*)(W_ih + EMBD*HD);  // ctx rows of W_ih
      for (int i = 0; i < 4; ++i) d4[tid + i*1024] = s4[tid + i*1024];
      __syncthreads();
      #pragma unroll
      for (int i = 0; i < 16; ++i) Wc[i] = stage[(rg*16 + i)*HD + c_];
      __syncthreads();
    }
    if (tid < HD){ h_lds[tid] = 0.f; hh_lds[tid] = 0.f; ctx_lds[tid] = 0.f; v_lds[tid] = v_attn[tid]; }
    __syncthreads();
  }

  const float* exb = ex + (long)b * TLEN * HD;

  for (int t = 0; t < TLEN; ++t){
    if (tid < HD) ex_lds[tid] = exb[t * HD + tid];   // prefetch, covered by later syncs

    if (t > 0){
      // ---- phase 1: q = h@W_attn ; k_new = h@U_attn ; hh = h@W_hh ; archive h as hid[t-1]
      {
        float aq = 0.f, ak = 0.f, ah = 0.f;
        const float4* h4 = (const float4*)h_lds;
        #pragma unroll
        for (int i4 = 0; i4 < 4; ++i4){
          float4 hv = h4[rg*4 + i4];
          aq += hv.x*Wa[i4*4+0] + hv.y*Wa[i4*4+1] + hv.z*Wa[i4*4+2] + hv.w*Wa[i4*4+3];
          ak += hv.x*Ua[i4*4+0] + hv.y*Ua[i4*4+1] + hv.z*Ua[i4*4+2] + hv.w*Ua[i4*4+3];
          ah += hv.x*Wh[i4*4+0] + hv.y*Wh[i4*4+1] + hv.z*Wh[i4*4+2] + hv.w*Wh[i4*4+3];
        }
        #pragma unroll
        for (int m = 1; m < 8; m <<= 1){
          aq += __shfl_xor(aq, m); ak += __shfl_xor(ak, m); ah += __shfl_xor(ah, m);
        }
        if (rg == 0){
          q_lds[c_]  = aq;
          hh_lds[c_] = ah;
          keys[(t-1)*HD + c_] = __half_as_ushort(__float2half(ak));
          hid [(t-1)*HD + c_] = __half_as_ushort(__float2half(h_lds[c_]));
        }
      }
      __syncthreads();  // S1

      // ---- phase 2: scores[s] = v . tanh(q + keys[s]) for s < t (wave per s, 2 cols/lane)
      {
        float2 qv = *(const float2*)&q_lds[lane*2];
        float2 vv = *(const float2*)&v_lds[lane*2];
        for (int s = wv; s < t; s += 16){
          __half2 kp = *(const __half2*)&keys[s*HD + lane*2];
          float2 kf = __half22float2(kp);
          float p = tanhfast(qv.x + kf.x)*vv.x + tanhfast(qv.y + kf.y)*vv.y;
          #pragma unroll
          for (int m = 1; m < 64; m <<= 1) p += __shfl_xor(p, m);
          if (lane == 0) scores[s] = p;
        }
      }
      __syncthreads();  // S2

      // ---- phase 3a: softmax over s<t (wave 0)
      if (wv == 0){
        float vals[4]; float mx = -3.0e38f;
        #pragma unroll
        for (int j = 0; j < 4; ++j){
          int s = lane + j*64;
          vals[j] = (s < t) ? scores[s] : -3.0e38f;
          mx = fmaxf(mx, vals[j]);
        }
        #pragma unroll
        for (int m = 1; m < 64; m <<= 1) mx = fmaxf(mx, __shfl_xor(mx, m));
        float sum = 0.f;
        #pragma unroll
        for (int j = 0; j < 4; ++j){
          int s = lane + j*64;
          if (s < t){
            float e = __builtin_amdgcn_exp2f((vals[j] - mx) * 1.4426950408889634f);
            scores[s] = e; sum += e;
          }
        }
        #pragma unroll
        for (int m = 1; m < 64; m <<= 1) sum += __shfl_xor(sum, m);
        if (lane == 0) zr[0] = 1.0f / sum;
      }
      __syncthreads();  // S3

      // ---- phase 3b: ctx = sum_s w_s * hid[s] (wave-partitioned partials)
      {
        float a0 = 0.f, a1 = 0.f;
        for (int s = wv; s < t; s += 16){
          float e = scores[s];
          __half2 hp = *(const __half2*)&hid[s*HD + lane*2];
          float2 hf = __half22float2(hp);
          a0 += e * hf.x; a1 += e * hf.y;
        }
        pp[wv*HD + lane*2]     = a0;
        pp[wv*HD + lane*2 + 1] = a1;
      }
      __syncthreads();  // S4
      if (tid < HD){
        float s0 = 0.f;
        #pragma unroll
        for (int g = 0; g < 16; ++g) s0 += pp[g*HD + tid];
        ctx_lds[tid] = s0 * zr[0];
      }
      __syncthreads();  // S5
    } else {
      __syncthreads();  // cover ex_lds prefetch at t=0
    }

    // ---- phase 4: h_new = tanh(ex + hh + ctx@W_ih_ctx); (hh,ctx are 0 at t=0)
    {
      float ac = 0.f;
      const float4* ct4 = (const float4*)ctx_lds;
      #pragma unroll
      for (int i4 = 0; i4 < 4; ++i4){
        float4 cv = ct4[rg*4 + i4];
        ac += cv.x*Wc[i4*4+0] + cv.y*Wc[i4*4+1] + cv.z*Wc[i4*4+2] + cv.w*Wc[i4*4+3];
      }
      #pragma unroll
      for (int m = 1; m < 8; m <<= 1) ac += __shfl_xor(ac, m);
      if (rg == 0){
        float pre = ex_lds[c_] + hh_lds[c_] + ac;
        float hn = tanhfast(pre);
        h_lds[c_] = hn;
        out_bf[((long)b*TLEN + t)*HD + c_] = f2bf(hn);
        if (t == TLEN-1) h_final[b*HD + c_] = hn;
      }
    }
    __syncthreads();  // S6: h visible to next step
  }
}

// ---------------- logits GEMM: [2048,128]bf16 @ [128,32000] (Wbt is [32000,128]) + bias ----------------
__launch_bounds__(256, 2)
__global__ void gemm_kernel(const unsigned short* __restrict__ A, const unsigned short* __restrict__ Bt,
                            const float* __restrict__ bias, float* __restrict__ C){
  __shared__ char sAB[65536];
  char* sA = sAB;
  char* sB = sAB + 32768;
  const int tid = threadIdx.x;
  const int lane = tid & 63, wv = tid >> 6;
  const int n0 = blockIdx.x * 128, m0 = blockIdx.y * 128;
  const char* Ab = (const char*)A + (long)m0 * 256;
  const char* Bb = (const char*)Bt + (long)n0 * 256;

  #pragma unroll
  for (int it = 0; it < 8; ++it){
    int p  = it*4096 + wv*1024 + lane*16;
    int ps = p ^ (((p >> 8) & 7) << 4);      // pre-swizzled source, linear LDS dest (rule 21)
    gload_lds16(Ab + ps, sA + it*4096 + wv*1024);
    gload_lds16(Bb + ps, sB + it*4096 + wv*1024);
  }
  __syncthreads();

  f32x4 acc[2][8] = {};
  const int r15 = lane & 15, r4 = lane >> 4;
  #pragma unroll
  for (int kk = 0; kk < 4; ++kk){
    short8v af[2], bfr[8];
    #pragma unroll
    for (int mi = 0; mi < 2; ++mi){
      int row = wv*32 + mi*16 + r15;
      int off = row*256 + kk*64 + r4*16;
      af[mi] = *(const short8v*)(sA + (off ^ ((row & 7) << 4)));
    }
    #pragma unroll
    for (int ni = 0; ni < 8; ++ni){
      int row = ni*16 + r15;
      int off = row*256 + kk*64 + r4*16;
      bfr[ni] = *(const short8v*)(sB + (off ^ ((row & 7) << 4)));
    }
    #pragma unroll
    for (int ni = 0; ni < 8; ++ni)
      #pragma unroll
      for (int mi = 0; mi < 2; ++mi)
        acc[mi][ni] = __builtin_amdgcn_mfma_f32_16x16x32_bf16(af[mi], bfr[ni], acc[mi][ni], 0, 0, 0);
  }

  #pragma unroll
  for (int mi = 0; mi < 2; ++mi){
    int rbase = m0 + wv*32 + mi*16 + r4*4;
    #pragma unroll
    for (int ni = 0; ni < 8; ++ni){
      int col = n0 + ni*16 + r15;
      float bv = bias[col];
      #pragma unroll
      for (int j = 0; j < 4; ++j)
        C[(long)(rbase + j) * VOCAB + col] = acc[mi][ni][j] + bv;
    }
  }
}

extern "C" void kernel_launch(void* const* d_in, const int* in_sizes, int n_in,
                              void* d_out, int out_size, void* d_ws, size_t ws_size,
                              hipStream_t stream){
  const int*   x      = (const int*)d_in[0];
  const float* emb    = (const float*)d_in[1];
  const float* W_attn = (const float*)d_in[2];
  const float* U_attn = (const float*)d_in[3];
  const float* v_attn = (const float*)d_in[4];
  const float* W_ih   = (const float*)d_in[5];
  const float* b_ih   = (const float*)d_in[6];
  const float* W_hh   = (const float*)d_in[7];
  const float* b_hh   = (const float*)d_in[8];
  const float* W_out  = (const float*)d_in[9];
  const float* b_out  = (const float*)d_in[10];

  float* logits  = (float*)d_out;
  float* h_final = logits + (long)BATCH * TLEN * VOCAB;

  char* ws = (char*)d_ws;
  float*          ex   = (float*)ws;                               // 1 MB
  unsigned short* Wbt  = (unsigned short*)(ws + 1048576);          // 8.192 MB
  unsigned short* outb = (unsigned short*)(ws + 1048576 + 8192000);// 0.5 MB

  prep_ex_kernel<<<BATCH*TLEN, HD, 0, stream>>>(x, emb, W_ih, b_ih, b_hh, ex);
  prep_wt_kernel<<<dim3(VOCAB/32, HD/32), 256, 0, stream>>>(W_out, Wbt);

  const int ldsBytes = 2*TLEN*HD*2 + (6*HD + TLEN + 16*HD + 4) * 4;  // 143,380 B
  hipFuncSetAttribute((const void*)scan_kernel, hipFuncAttributeMaxDynamicSharedMemorySize, ldsBytes);
  scan_kernel<<<BATCH, 1024, ldsBytes, stream>>>(W_attn, U_attn, v_attn, W_ih, W_hh, ex, outb, h_final);

  gemm_kernel<<<dim3(VOCAB/128, (BATCH*TLEN)/128), 256, 0, stream>>>(outb, Wbt, b_out, logits);
}

// Round 3
// 1175.051 us; speedup vs baseline: 1.2335x; 1.2335x over previous
//
#include <hip/hip_runtime.h>
#include <hip/hip_fp16.h>
#include <hip/hip_bf16.h>
#include <cstdint>

#define TLEN  256
#define HD    128
#define BATCH 8
#define VOCAB 32000
#define EMBD  32

typedef __attribute__((ext_vector_type(8))) short short8v;
typedef __attribute__((ext_vector_type(8))) unsigned short ushort8v;
typedef __attribute__((ext_vector_type(4))) float f32x4;

__device__ __forceinline__ float tanhfast(float x){
  float e = __builtin_amdgcn_exp2f(x * 2.8853900817779268f);
  return 1.0f - 2.0f * __builtin_amdgcn_rcpf(e + 1.0f);
}
__device__ __forceinline__ unsigned short f2bf(float f){
  unsigned u = __float_as_uint(f);
  return (unsigned short)((u + 0x7fffu + ((u >> 16) & 1u)) >> 16);
}
__device__ __forceinline__ float h2f(unsigned short u){
  return __half2float(__ushort_as_half(u));
}
__device__ __forceinline__ unsigned short f2h(float f){
  return __half_as_ushort(__float2half(f));
}
__device__ __forceinline__ void gload_lds16(const void* g, void* l){
  __builtin_amdgcn_global_load_lds((const __attribute__((address_space(1))) void*)g,
                                   (__attribute__((address_space(3))) void*)l, 16, 0, 0);
}

// ---------------- prep 1: ex[b,t,c] = emb[x[b,t]] @ W_ih[0:32] + b_ih + b_hh ----------------
__global__ void prep_ex_kernel(const int* __restrict__ x, const float* __restrict__ emb,
                               const float* __restrict__ W_ih, const float* __restrict__ b_ih,
                               const float* __restrict__ b_hh, float* __restrict__ ex){
  int bt = blockIdx.x;
  int c  = threadIdx.x;
  int ix = x[bt];
  const float* er = emb + (long)ix * EMBD;
  float acc = b_ih[c] + b_hh[c];
  #pragma unroll
  for (int e = 0; e < EMBD; ++e) acc += er[e] * W_ih[e * HD + c];
  ex[bt * HD + c] = acc;
}

// ---------------- prep 2: Wbt[n][k] = bf16(W_out[k][n]) ----------------
__global__ void prep_wt_kernel(const float* __restrict__ W_out, unsigned short* __restrict__ Wbt){
  __shared__ float tile[32][33];
  int tx = threadIdx.x & 31, ty = threadIdx.x >> 5;
  int n0 = blockIdx.x * 32, k0 = blockIdx.y * 32;
  #pragma unroll
  for (int j = 0; j < 4; ++j){
    int k = ty + j * 8;
    tile[k][tx] = W_out[(long)(k0 + k) * VOCAB + n0 + tx];
  }
  __syncthreads();
  #pragma unroll
  for (int j = 0; j < 4; ++j){
    int n = ty + j * 8;
    Wbt[(long)(n0 + n) * HD + k0 + tx] = f2bf(tile[tx][n]);
  }
}

// ---------------- scan: one workgroup per batch element ----------------
// LDS: keys[256][128] fp16 swizzled | hid[256][128] fp16 swizzled | fp32 scratch
__launch_bounds__(1024)
__global__ void scan_kernel(const float* __restrict__ W_attn, const float* __restrict__ U_attn,
                            const float* __restrict__ v_attn, const float* __restrict__ W_ih,
                            const float* __restrict__ W_hh, const float* __restrict__ ex,
                            unsigned short* __restrict__ out_bf, float* __restrict__ h_final){
  extern __shared__ char lds[];
  char* keysB = lds;                   // 64 KB, fp16, XOR-swizzled chunks
  char* hidB  = lds + 65536;           // 64 KB
  float* fbuf   = (float*)(lds + 131072);
  float* q_pad    = fbuf;              // 160 (80B-stride pad)
  float* h_pad    = fbuf + 160;        // 160
  float* ctx_pad  = fbuf + 320;        // 160
  float* hh_lds   = fbuf + 480;        // 128
  float* scores_e = fbuf + 608;        // 256
  float* pp       = fbuf + 864;        // 16
  float* v_pad    = fbuf + 880;        // 160

  const int b    = blockIdx.x;
  const int tid  = threadIdx.x;
  const int lane = tid & 63, wv = tid >> 6;
  const int c_   = tid >> 3, rg = tid & 7;      // phase 1/4 mapping
  const int sg   = lane >> 3, cg = lane & 7;    // phase 2/3 mapping

  // ---- init small buffers (before staging sync) ----
  if (tid < HD){ hh_lds[tid] = 0.f; v_pad[tid + (tid>>4)*4] = v_attn[tid]; }
  if (tid < 160) ctx_pad[tid] = 0.f;

  // ---- stage weights into VGPRs ----
  float Wa[16], Ua[16], Wh[16], Wc[16];
  {
    float* stage = (float*)lds;        // reuse keys+hid area
    float4* d4 = (float4*)stage;
    {
      const float4* s4 = (const float4*)W_attn;
      for (int i = 0; i < 4; ++i) d4[tid + i*1024] = s4[tid + i*1024];
      __syncthreads();
      #pragma unroll
      for (int i = 0; i < 16; ++i) Wa[i] = stage[(rg*16 + i)*HD + c_];
      __syncthreads();
    }
    {
      const float4* s4 = (const float4*)U_attn;
      for (int i = 0; i < 4; ++i) d4[tid + i*1024] = s4[tid + i*1024];
      __syncthreads();
      #pragma unroll
      for (int i = 0; i < 16; ++i) Ua[i] = stage[(rg*16 + i)*HD + c_];
      __syncthreads();
    }
    {
      const float4* s4 = (const float4*)W_hh;
      for (int i = 0; i < 4; ++i) d4[tid + i*1024] = s4[tid + i*1024];
      __syncthreads();
      #pragma unroll
      for (int i = 0; i < 16; ++i) Wh[i] = stage[(rg*16 + i)*HD + c_];
      __syncthreads();
    }
    {
      const float4* s4 = (const float4*)(W_ih + EMBD*HD);
      for (int i = 0; i < 4; ++i) d4[tid + i*1024] = s4[tid + i*1024];
      __syncthreads();
      #pragma unroll
      for (int i = 0; i < 16; ++i) Wc[i] = stage[(rg*16 + i)*HD + c_];
      __syncthreads();
    }
  }

  // ---- hoist v (cols cg*16..cg*16+15) into registers; constant over t ----
  float vreg[16];
  {
    const float4* v4 = (const float4*)(v_pad + cg*20);
    #pragma unroll
    for (int i = 0; i < 4; ++i){
      float4 vv = v4[i];
      vreg[i*4+0]=vv.x; vreg[i*4+1]=vv.y; vreg[i*4+2]=vv.z; vreg[i*4+3]=vv.w;
    }
  }

  const float* exb = ex + (long)b * TLEN * HD;

  for (int t = 0; t < TLEN; ++t){
    float exv = exb[t * HD + c_];      // register prefetch (used in phase 4)

    if (t > 0){
      // ---- phase 1: q = h@W_attn ; k = h@U_attn -> keys[t-1] ; hh = h@W_hh ----
      {
        float aq = 0.f, ak = 0.f, ah = 0.f;
        const float4* h4 = (const float4*)(h_pad + rg*20);
        #pragma unroll
        for (int i4 = 0; i4 < 4; ++i4){
          float4 hv = h4[i4];
          aq += hv.x*Wa[i4*4+0] + hv.y*Wa[i4*4+1] + hv.z*Wa[i4*4+2] + hv.w*Wa[i4*4+3];
          ak += hv.x*Ua[i4*4+0] + hv.y*Ua[i4*4+1] + hv.z*Ua[i4*4+2] + hv.w*Ua[i4*4+3];
          ah += hv.x*Wh[i4*4+0] + hv.y*Wh[i4*4+1] + hv.z*Wh[i4*4+2] + hv.w*Wh[i4*4+3];
        }
        #pragma unroll
        for (int m = 1; m < 8; m <<= 1){
          aq += __shfl_xor(aq, m); ak += __shfl_xor(ak, m); ah += __shfl_xor(ah, m);
        }
        if (rg == 0){
          q_pad[c_ + (c_>>4)*4] = aq;
          hh_lds[c_] = ah;
          int s = t - 1;
          *(unsigned short*)(keysB + s*256 + ((((c_>>4) ^ (s&7)) & 7)<<5) + ((c_&15)<<1)) = f2h(ak);
        }
      }
      __syncthreads();  // S1: q, keys[t-1], hh ready

      // ---- phase 2: e_s = exp(v . tanh(q + keys[s])), partial sums ----
      {
        float qreg[16];
        {
          const float4* q4 = (const float4*)(q_pad + cg*20);
          #pragma unroll
          for (int i = 0; i < 4; ++i){
            float4 qv = q4[i];
            qreg[i*4+0]=qv.x; qreg[i*4+1]=qv.y; qreg[i*4+2]=qv.z; qreg[i*4+3]=qv.w;
          }
        }
        float esum = 0.f;
        #pragma unroll
        for (int it = 0; it < 2; ++it){
          int s = wv*8 + sg + it*128;
          float e = 0.f;
          if (s < t){
            const char* kb = keysB + s*256 + (((cg ^ sg) & 7) << 5);
            ushort8v k0 = *(const ushort8v*)kb;
            ushort8v k1 = *(const ushort8v*)(kb + 16);
            float p = 0.f;
            #pragma unroll
            for (int j = 0; j < 8; ++j){
              p += vreg[j]     * tanhfast(qreg[j]     + h2f(k0[j]));
              p += vreg[8 + j] * tanhfast(qreg[8 + j] + h2f(k1[j]));
            }
            p += __shfl_xor(p, 1); p += __shfl_xor(p, 2); p += __shfl_xor(p, 4);
            e = __builtin_amdgcn_exp2f(p * 1.4426950408889634f);
            if (cg == 0) scores_e[s] = e;
          }
          esum += e;
        }
        // sg-bit reduce only: each s counted exactly once (cg replication does
        // NOT enter this sum — masks 8/16/32 are sg bits).
        esum += __shfl_xor(esum, 8); esum += __shfl_xor(esum, 16); esum += __shfl_xor(esum, 32);
        if (lane == 0) pp[wv] = esum;
      }
      __syncthreads();  // S2: scores_e, pp ready

      // ---- phase 3: ctx[col] = (sum_s e_s * hid[s][col]) / sum_e  (wave owns 8 cols) ----
      {
        float4 p0 = ((const float4*)pp)[0], p1 = ((const float4*)pp)[1];
        float4 p2 = ((const float4*)pp)[2], p3 = ((const float4*)pp)[3];
        float sum = (p0.x+p0.y+p0.z+p0.w) + (p1.x+p1.y+p1.z+p1.w)
                  + (p2.x+p2.y+p2.z+p2.w) + (p3.x+p3.y+p3.z+p3.w);
        float inv = __builtin_amdgcn_rcpf(sum);
        int col = wv*8 + cg;
        const char* hb = hidB + ((((col>>4) ^ sg) & 7)<<5) + ((col&15)<<1);
        float a0 = 0.f;
        for (int s = sg; s < t; s += 8){
          float e = scores_e[s];
          a0 += e * h2f(*(const unsigned short*)(hb + s*256));
        }
        a0 += __shfl_xor(a0, 8); a0 += __shfl_xor(a0, 16); a0 += __shfl_xor(a0, 32);
        if (sg == 0) ctx_pad[col + (col>>4)*4] = a0 * inv;
      }
      __syncthreads();  // S3: ctx ready
    }

    // ---- phase 4: h_new = tanh(ex + hh + ctx@Wc) ----
    {
      float ac = 0.f;
      const float4* ct4 = (const float4*)(ctx_pad + rg*20);
      #pragma unroll
      for (int i4 = 0; i4 < 4; ++i4){
        float4 cv = ct4[i4];
        ac += cv.x*Wc[i4*4+0] + cv.y*Wc[i4*4+1] + cv.z*Wc[i4*4+2] + cv.w*Wc[i4*4+3];
      }
      #pragma unroll
      for (int m = 1; m < 8; m <<= 1) ac += __shfl_xor(ac, m);
      if (rg == 0){
        float pre = exv + hh_lds[c_] + ac;
        float hn = tanhfast(pre);
        h_pad[c_ + (c_>>4)*4] = hn;
        *(unsigned short*)(hidB + t*256 + ((((c_>>4) ^ (t&7)) & 7)<<5) + ((c_&15)<<1)) = f2h(hn);
        out_bf[((long)b*TLEN + t)*HD + c_] = f2bf(hn);
        if (t == TLEN-1) h_final[b*HD + c_] = hn;
      }
    }
    __syncthreads();  // S4: h ready for next step
  }
}

// ---------------- logits GEMM: [2048,128]bf16 @ Wbt[32000,128]^T + bias ----------------
__launch_bounds__(256, 2)
__global__ void gemm_kernel(const unsigned short* __restrict__ A, const unsigned short* __restrict__ Bt,
                            const float* __restrict__ bias, float* __restrict__ C){
  __shared__ char sAB[65536];
  char* sA = sAB;
  char* sB = sAB + 32768;
  const int tid = threadIdx.x;
  const int lane = tid & 63, wv = tid >> 6;
  const int n0 = blockIdx.x * 128, m0 = blockIdx.y * 128;
  const char* Ab = (const char*)A + (long)m0 * 256;
  const char* Bb = (const char*)Bt + (long)n0 * 256;

  #pragma unroll
  for (int it = 0; it < 8; ++it){
    int p  = it*4096 + wv*1024 + lane*16;
    int ps = p ^ (((p >> 8) & 7) << 4);
    gload_lds16(Ab + ps, sA + it*4096 + wv*1024);
    gload_lds16(Bb + ps, sB + it*4096 + wv*1024);
  }
  __syncthreads();

  f32x4 acc[2][8] = {};
  const int r15 = lane & 15, r4 = lane >> 4;
  #pragma unroll
  for (int kk = 0; kk < 4; ++kk){
    short8v af[2], bfr[8];
    #pragma unroll
    for (int mi = 0; mi < 2; ++mi){
      int row = wv*32 + mi*16 + r15;
      int off = row*256 + kk*64 + r4*16;
      af[mi] = *(const short8v*)(sA + (off ^ ((row & 7) << 4)));
    }
    #pragma unroll
    for (int ni = 0; ni < 8; ++ni){
      int row = ni*16 + r15;
      int off = row*256 + kk*64 + r4*16;
      bfr[ni] = *(const short8v*)(sB + (off ^ ((row & 7) << 4)));
    }
    #pragma unroll
    for (int ni = 0; ni < 8; ++ni)
      #pragma unroll
      for (int mi = 0; mi < 2; ++mi)
        acc[mi][ni] = __builtin_amdgcn_mfma_f32_16x16x32_bf16(af[mi], bfr[ni], acc[mi][ni], 0, 0, 0);
  }

  #pragma unroll
  for (int mi = 0; mi < 2; ++mi){
    int rbase = m0 + wv*32 + mi*16 + r4*4;
    #pragma unroll
    for (int ni = 0; ni < 8; ++ni){
      int col = n0 + ni*16 + r15;
      float bv = bias[col];
      #pragma unroll
      for (int j = 0; j < 4; ++j)
        C[(long)(rbase + j) * VOCAB + col] = acc[mi][ni][j] + bv;
    }
  }
}

extern "C" void kernel_launch(void* const* d_in, const int* in_sizes, int n_in,
                              void* d_out, int out_size, void* d_ws, size_t ws_size,
                              hipStream_t stream){
  const int*   x      = (const int*)d_in[0];
  const float* emb    = (const float*)d_in[1];
  const float* W_attn = (const float*)d_in[2];
  const float* U_attn = (const float*)d_in[3];
  const float* v_attn = (const float*)d_in[4];
  const float* W_ih   = (const float*)d_in[5];
  const float* b_ih   = (const float*)d_in[6];
  const float* W_hh   = (const float*)d_in[7];
  const float* b_hh   = (const float*)d_in[8];
  const float* W_out  = (const float*)d_in[9];
  const float* b_out  = (const float*)d_in[10];

  float* logits  = (float*)d_out;
  float* h_final = logits + (long)BATCH * TLEN * VOCAB;

  char* ws = (char*)d_ws;
  float*          ex   = (float*)ws;                                // 1 MB
  unsigned short* Wbt  = (unsigned short*)(ws + 1048576);           // 8.192 MB
  unsigned short* outb = (unsigned short*)(ws + 1048576 + 8192000); // 0.5 MB

  prep_ex_kernel<<<BATCH*TLEN, HD, 0, stream>>>(x, emb, W_ih, b_ih, b_hh, ex);
  prep_wt_kernel<<<dim3(VOCAB/32, HD/32), 256, 0, stream>>>(W_out, Wbt);

  const int ldsBytes = 131072 + 1040*4;   // 135,232 B
  hipFuncSetAttribute((const void*)scan_kernel, hipFuncAttributeMaxDynamicSharedMemorySize, ldsBytes);
  scan_kernel<<<BATCH, 1024, ldsBytes, stream>>>(W_attn, U_attn, v_attn, W_ih, W_hh, ex, outb, h_final);

  gemm_kernel<<<dim3(VOCAB/128, (BATCH*TLEN)/128), 256, 0, stream>>>(outb, Wbt, b_out, logits);
}